// Round 11
// baseline (72.389 us; speedup 1.0000x reference)
//
#include <hip/hip_runtime.h>

#define B_ 2
#define N_ 2048
#define DIM_ 1024
#define H_ 8
#define DH_ 64
#define DI_ 512
#define WIN_ 512
#define NCPAD 1664  // 13*128 padded proj cols: 512 q | 1024 kv | 8 g | 8 mix | 112 pad

typedef __bf16 bf16x8 __attribute__((ext_vector_type(8)));
typedef unsigned short ushortx8 __attribute__((ext_vector_type(8)));
typedef float floatx4 __attribute__((ext_vector_type(4)));

#define MFMA16(a, b, c) __builtin_amdgcn_mfma_f32_16x16x32_bf16((a), (b), (c), 0, 0, 0)

__device__ inline unsigned short f2bf(float f) {
  union { float f; unsigned u; } v; v.f = f;
  unsigned r = v.u + 0x7FFFu + ((v.u >> 16) & 1u);
  return (unsigned short)(r >> 16);
}
__device__ inline float bf2f(unsigned short u) {
  union { unsigned u; float f; } v; v.u = ((unsigned)u) << 16; return v.f;
}
__device__ inline float sigmoidf_(float x) { return 1.0f / (1.0f + __expf(-x)); }

__device__ __forceinline__ void gload_lds16(const unsigned short* g, unsigned short* l) {
  __builtin_amdgcn_global_load_lds(
      (const __attribute__((address_space(1))) void*)g,
      (__attribute__((address_space(3))) void*)l,
      16, 0, 0);
}

// ================= fused prep: trig table | tokens->bf16 | weight transposes =================
__global__ __launch_bounds__(256) void k_prep(const float* __restrict__ tokens,
                                              const float* __restrict__ Wq,
                                              const float* __restrict__ Wkv,
                                              const float* __restrict__ Wo,
                                              const float* __restrict__ Wg,
                                              const float* __restrict__ Wmix,
                                              unsigned short* __restrict__ tokb,
                                              unsigned short* __restrict__ wcat,
                                              unsigned short* __restrict__ wot,
                                              float2* __restrict__ cs) {
  __shared__ float t32[32][33];
  const int bid = blockIdx.x;
  const int tid = threadIdx.x;
  if (bid < 256) {
    int i = bid * 256 + tid;
    int n = i >> 5, t2 = i & 31;
    float inv = __expf(-(float)t2 * 0.2878231366242557f);  // ln(10000)/32
    float sv, cv;
    sincosf((float)n * inv, &sv, &cv);
    cs[i] = make_float2(cv, sv);
    return;
  }
  if (bid < 4352) {
    int i = (bid - 256) * 256 + tid;
    float4 v = reinterpret_cast<const float4*>(tokens)[i];
    ushort4 r;
    r.x = f2bf(v.x); r.y = f2bf(v.y); r.z = f2bf(v.z); r.w = f2bf(v.w);
    reinterpret_cast<ushort4*>(tokb)[i] = r;
    return;
  }
  if (bid >= 6400) {
    int idx = (bid - 6400) * 256 + tid;
    int j = idx >> 10;
    int c = idx & 1023;
    float v = (j < 8) ? Wg[c * 8 + j] : Wmix[c * 8 + (j - 8)];
    wcat[(size_t)(1536 + j) * 1024 + c] = f2bf(v);
    return;
  }
  const float* in;
  unsigned short* out;
  int Rin, Cin, c0, r0;
  if (bid < 4864) {
    int t = bid - 4352; in = Wq; out = wcat; Rin = 1024; Cin = 512;
    c0 = (t & 15) * 32; r0 = (t >> 4) * 32;
  } else if (bid < 5888) {
    int t = bid - 4864; in = Wkv; out = wcat + 512 * 1024; Rin = 1024; Cin = 1024;
    c0 = (t & 31) * 32; r0 = (t >> 5) * 32;
  } else {
    int t = bid - 5888; in = Wo; out = wot; Rin = 512; Cin = 1024;
    c0 = (t & 31) * 32; r0 = (t >> 5) * 32;
  }
  const int tx = tid & 31, ty = tid >> 5;
#pragma unroll
  for (int i = 0; i < 4; ++i)
    t32[ty + i * 8][tx] = in[(size_t)(r0 + ty + i * 8) * Cin + c0 + tx];
  __syncthreads();
#pragma unroll
  for (int i = 0; i < 4; ++i)
    out[(size_t)(c0 + ty + i * 8) * Rin + r0 + tx] = f2bf(t32[tx][ty + i * 8]);
}

// ================= 128x64 BK=64 GEMM: dbuf + stage-early + XOR-swizzled LDS + XCD-chunked =================
// 48 KB LDS -> 3 blocks/CU; big grids give ~3 resident blocks/CU (m114 overlap regime).
template <typename OUT>
__global__ __launch_bounds__(256) void k_gemmT(const unsigned short* __restrict__ A,
                                               const unsigned short* __restrict__ Bt,
                                               OUT* __restrict__ C,
                                               int M, int Nc, int K) {
  __shared__ __align__(16) unsigned short As[2][128 * 64];
  __shared__ __align__(16) unsigned short Bs[2][64 * 64];
  const int tid = threadIdx.x;
  const int lane = tid & 63;
  const int wid = tid >> 6;
  const int nwgx = gridDim.x;
  const int flat = blockIdx.y * nwgx + blockIdx.x;
  const int cpx = (nwgx * gridDim.y) >> 3;  // grid % 8 == 0 always here
  const int swz = (flat & 7) * cpx + (flat >> 3);
  const int m0 = (swz / nwgx) * 128;
  const int n0 = (swz % nwgx) * 64;
  const int wr = (wid >> 1) * 64;
  const int wc = (wid & 1) * 32;
  const int lr = lane & 15;
  const int hi = lane >> 4;
  const int grow = tid >> 3;
  const int gchk = tid & 7;
  const int csw = gchk ^ (grow & 7);
  const unsigned short* aP = A + (size_t)(m0 + grow) * K + csw * 8;
  const unsigned short* bP = Bt + (size_t)(n0 + grow) * K + csw * 8;
  const int ldst = grow * 64 + gchk * 8;
  const int off0 = ((hi ^ (lr & 7)) << 3);
  floatx4 acc[4][2] = {};
  const int T = K >> 6;
#pragma unroll
  for (int r = 0; r < 4; ++r) gload_lds16(aP + (size_t)(r * 32) * K, &As[0][ldst + r * 2048]);
#pragma unroll
  for (int r = 0; r < 2; ++r) gload_lds16(bP + (size_t)(r * 32) * K, &Bs[0][ldst + r * 2048]);
  __syncthreads();
  for (int t = 0; t < T; ++t) {
    const int cur = t & 1;
    if (t + 1 < T) {
      const int nxt = cur ^ 1;
      const int k1 = (t + 1) << 6;
#pragma unroll
      for (int r = 0; r < 4; ++r) gload_lds16(aP + k1 + (size_t)(r * 32) * K, &As[nxt][ldst + r * 2048]);
#pragma unroll
      for (int r = 0; r < 2; ++r) gload_lds16(bP + k1 + (size_t)(r * 32) * K, &Bs[nxt][ldst + r * 2048]);
    }
#pragma unroll
    for (int kk = 0; kk < 2; ++kk) {
      const int off = off0 ^ (kk << 5);
      bf16x8 af[4], bfr[2];
#pragma unroll
      for (int i = 0; i < 4; ++i)
        af[i] = *reinterpret_cast<const bf16x8*>(&As[cur][(wr + i * 16 + lr) * 64 + off]);
#pragma unroll
      for (int j = 0; j < 2; ++j)
        bfr[j] = *reinterpret_cast<const bf16x8*>(&Bs[cur][(wc + j * 16 + lr) * 64 + off]);
#pragma unroll
      for (int i = 0; i < 4; ++i)
#pragma unroll
        for (int j = 0; j < 2; ++j)
          acc[i][j] = MFMA16(af[i], bfr[j], acc[i][j]);
    }
    __syncthreads();
  }
  const int r0 = hi << 2;
#pragma unroll
  for (int i = 0; i < 4; ++i)
#pragma unroll
    for (int j = 0; j < 2; ++j) {
      OUT* cp = C + (size_t)(m0 + wr + i * 16 + r0) * Nc + n0 + wc + j * 16 + lr;
#pragma unroll
      for (int r = 0; r < 4; ++r) {
        if constexpr (sizeof(OUT) == 4) cp[(size_t)r * Nc] = acc[i][j][r];
        else                            cp[(size_t)r * Nc] = f2bf(acc[i][j][r]);
      }
    }
}

// ================= fused post: RoPE Q/K + gates + V lerp/tile =================
__global__ __launch_bounds__(512) void k_postv(const unsigned short* __restrict__ proj,
                                               const float* __restrict__ vres,
                                               const float2* __restrict__ cs,
                                               unsigned short* __restrict__ Qb,
                                               unsigned short* __restrict__ Kb,
                                               unsigned short* __restrict__ Vt,
                                               float* __restrict__ gates) {
  const int w = threadIdx.x >> 6, l = threadIdx.x & 63;
  const int row = blockIdx.x * 8 + w;
  const int b = row >> 11, n = row & (N_ - 1);
  const unsigned short* pr = proj + (size_t)row * NCPAD;
  if (l < H_) gates[(size_t)(b * H_ + l) * N_ + n] = sigmoidf_(bf2f(pr[1536 + l]));
  ushortx8 qv = *reinterpret_cast<const ushortx8*>(pr + 8 * l);
  ushortx8 kv = *reinterpret_cast<const ushortx8*>(pr + 512 + 8 * l);
  const int t2b = 4 * (l & 7);
  ushortx8 qo, ko;
#pragma unroll
  for (int p = 0; p < 4; ++p) {
    float2 c2 = cs[n * 32 + t2b + p];
    float q0 = bf2f(qv[2 * p]), q1 = bf2f(qv[2 * p + 1]);
    float k0 = bf2f(kv[2 * p]), k1 = bf2f(kv[2 * p + 1]);
    qo[2 * p]     = f2bf((q0 * c2.x - q1 * c2.y) * 0.125f);
    qo[2 * p + 1] = f2bf((q1 * c2.x + q0 * c2.y) * 0.125f);
    ko[2 * p]     = f2bf(k0 * c2.x - k1 * c2.y);
    ko[2 * p + 1] = f2bf(k1 * c2.x + k0 * c2.y);
  }
  const int h = l >> 3;
  const size_t off = ((size_t)(b * H_ + h) * N_ + n) * DH_ + 8 * (l & 7);
  *reinterpret_cast<ushortx8*>(Qb + off) = qo;
  *reinterpret_cast<ushortx8*>(Kb + off) = ko;
  const int hv = w;
  const int d = l;
  const int base_row = blockIdx.x * 8;
  const int bb = base_row >> 11;
  ushortx8 acc;
#pragma unroll
  for (int r = 0; r < 8; ++r) {
    const unsigned short* pr2 = proj + (size_t)(base_row + r) * NCPAD;
    const float mix = sigmoidf_(bf2f(pr2[1544 + hv]));
    const float pv = bf2f(pr2[1024 + hv * 64 + d]);
    const float vr = vres[((size_t)(bb * H_ + hv) * N_ + ((base_row + r) & (N_ - 1))) * DH_ + d];
    acc[r] = f2bf(pv + (vr - pv) * mix);
  }
  *reinterpret_cast<ushortx8*>(Vt + (size_t)(bb * H_ + hv) * N_ * DH_ +
                               (size_t)(blockIdx.x & 255) * 512 + d * 8) = acc;
}

// ================= 4-wave LDS-staged windowed attention =================
__global__ __launch_bounds__(256) void k_attn4(const unsigned short* __restrict__ Qb,
                                               const unsigned short* __restrict__ Kb,
                                               const unsigned short* __restrict__ Vt,
                                               const float* __restrict__ gates,
                                               unsigned short* __restrict__ Og) {
  __shared__ __align__(16) unsigned short Ks[2][64 * 64];
  __shared__ __align__(16) unsigned short Vs[2][64 * 64];
  __shared__ __align__(16) unsigned short Ps[4][16 * 72];
  const int bid = (int)blockIdx.x;
  const int xcd = bid & 7;
  const int seq = bid >> 3;
  const int bh = xcd * 2 + (seq >> 5);
  const int s = seq & 31;
  const int qt = (s & 1) ? (s >> 1) : (31 - (s >> 1));
  const int b = bh >> 3, h = bh & 7;
  const int qi0 = qt * 64;
  const int tid = threadIdx.x;
  const int w = tid >> 6;
  const int lane = tid & 63;
  const int lr = lane & 15;
  const int hi = lane >> 4;
  const int lk = hi << 3;
  const int qw0 = qi0 + w * 16;
  const unsigned short* Qh = Qb + (size_t)bh * N_ * DH_;
  const unsigned short* Kh = Kb + (size_t)bh * N_ * DH_;
  const unsigned short* Vh = Vt + (size_t)bh * N_ * DH_;
  bf16x8 aq0 = *reinterpret_cast<const bf16x8*>(Qh + (qw0 + lr) * DH_ + lk);
  bf16x8 aq1 = *reinterpret_cast<const bf16x8*>(Qh + (qw0 + lr) * DH_ + 32 + lk);
  floatx4 o[4] = {};
  float lsum[4] = {0.f, 0.f, 0.f, 0.f};

  const int s_row = tid >> 3;
  const int s_chk = tid & 7;

  auto stage = [&](int bufi, int j0) {
#pragma unroll
    for (int p = 0; p < 2; ++p) {
      const int row = s_row + p * 32;
      const int csw = s_chk ^ (row & 7);
      gload_lds16(Kh + (size_t)(j0 + row) * DH_ + csw * 8, &Ks[bufi][(row * 8 + s_chk) * 8]);
    }
#pragma unroll
    for (int p = 0; p < 2; ++p) {
      const int flat = p * 256 + tid;
      gload_lds16(Vh + (size_t)j0 * DH_ + flat * 8, &Vs[bufi][flat * 8]);
    }
  };

  auto compute = [&](int bufi, int j0, bool maskLo, bool maskHi) {
    floatx4 c[4];
    __builtin_amdgcn_s_setprio(1);
#pragma unroll
    for (int cc = 0; cc < 4; ++cc) {
      const int row = 16 * cc + lr;
      const int sw = row & 7;
      bf16x8 kf0 = *reinterpret_cast<const bf16x8*>(&Ks[bufi][row * 64 + ((hi ^ sw) << 3)]);
      bf16x8 kf1 = *reinterpret_cast<const bf16x8*>(&Ks[bufi][row * 64 + (((hi + 4) ^ sw) << 3)]);
      floatx4 a = {};
      a = MFMA16(aq0, kf0, a);
      a = MFMA16(aq1, kf1, a);
      c[cc] = a;
    }
    __builtin_amdgcn_s_setprio(0);
#pragma unroll
    for (int cc = 0; cc < 4; ++cc)
#pragma unroll
      for (int r = 0; r < 4; ++r) {
        const int i = qw0 + hi * 4 + r;
        const int j = j0 + 16 * cc + lr;
        float sc = c[cc][r];
        if (maskHi && j > i) sc = -1e30f;
        if (maskLo && (i - j) > WIN_) sc = -1e30f;
        const float p = __expf(sc);
        lsum[r] += p;
        Ps[w][(hi * 4 + r) * 72 + 16 * cc + lr] = f2bf(p);
      }
    bf16x8 pa0 = *reinterpret_cast<const bf16x8*>(&Ps[w][lr * 72 + lk]);
    bf16x8 pa1 = *reinterpret_cast<const bf16x8*>(&Ps[w][lr * 72 + 32 + lk]);
    __builtin_amdgcn_s_setprio(1);
#pragma unroll
    for (int nb = 0; nb < 4; ++nb) {
      bf16x8 v0 = *reinterpret_cast<const bf16x8*>(&Vs[bufi][lk * 64 + nb * 128 + lr * 8]);
      bf16x8 v1 = *reinterpret_cast<const bf16x8*>(&Vs[bufi][(32 + lk) * 64 + nb * 128 + lr * 8]);
      o[nb] = MFMA16(pa0, v0, o[nb]);
      o[nb] = MFMA16(pa1, v1, o[nb]);
    }
    __builtin_amdgcn_s_setprio(0);
  };

  const int jlo = (qi0 >= WIN_) ? (qi0 - WIN_) : 0;
  const int niter = (qi0 + 64 - jlo) >> 6;
  const bool needLo = (qi0 >= WIN_);

  stage(0, jlo);
  __syncthreads();
  int bufi = 0;
  for (int t = 0; t < niter; ++t) {
    const int j0 = jlo + t * 64;
    if (t + 1 < niter) stage(bufi ^ 1, j0 + 64);
    compute(bufi, j0, needLo && t == 0, t == niter - 1);
    __syncthreads();
    bufi ^= 1;
  }

#pragma unroll
  for (int r = 0; r < 4; ++r) {
    float ls = lsum[r];
#pragma unroll
    for (int off = 1; off < 16; off <<= 1) ls += __shfl_xor(ls, off, 16);
    const int i = qw0 + hi * 4 + r;
    const float g = gates[(size_t)bh * N_ + i] * __builtin_amdgcn_rcpf(ls);
#pragma unroll
    for (int nb = 0; nb < 4; ++nb)
      Og[((size_t)(b * N_ + i)) * DI_ + h * DH_ + nb * 16 + lr] = f2bf(o[nb][r] * g);
  }
}

extern "C" void kernel_launch(void* const* d_in, const int* in_sizes, int n_in,
                              void* d_out, int out_size, void* d_ws, size_t ws_size,
                              hipStream_t stream) {
  const float* tokens = (const float*)d_in[0];
  const float* vres   = (const float*)d_in[1];
  const float* Wq     = (const float*)d_in[2];
  const float* Wkv    = (const float*)d_in[3];
  const float* Wo     = (const float*)d_in[4];
  const float* Wg     = (const float*)d_in[5];
  const float* Wmix   = (const float*)d_in[6];
  float* out = (float*)d_out;
  char* ws = (char*)d_ws;
  unsigned short* tokb = (unsigned short*)(ws);              // 8,388,608
  unsigned short* wcat = (unsigned short*)(ws + 8388608);    // 3,407,872
  unsigned short* wot  = (unsigned short*)(ws + 11796480);   // 1,048,576
  unsigned short* proj = (unsigned short*)(ws + 12845056);   // 13,631,488
  unsigned short* Qb   = (unsigned short*)(ws + 26476544);   // 4,194,304
  unsigned short* Kb   = (unsigned short*)(ws + 30670848);   // 4,194,304
  unsigned short* Vt   = (unsigned short*)(ws + 34865152);   // 4,194,304
  float*          gates= (float*)(ws + 39059456);            // 131,072
  unsigned short* Og   = (unsigned short*)(ws + 39190528);   // 4,194,304
  float2*         cs   = (float2*)(ws + 43384832);           // 524,288
  (void)in_sizes; (void)n_in; (void)out_size; (void)ws_size;

  k_prep<<<6464, 256, 0, stream>>>(tokens, Wq, Wkv, Wo, Wg, Wmix, tokb, wcat, wot, cs);

  dim3 g1(NCPAD / 64, (B_ * N_) / 128);  // 26 x 32 = 832 blocks
  k_gemmT<unsigned short><<<g1, 256, 0, stream>>>(tokb, wcat, proj, B_ * N_, NCPAD, DIM_);

  k_postv<<<(B_ * N_) / 8, 512, 0, stream>>>(proj, vres, cs, Qb, Kb, Vt, gates);

  k_attn4<<<512, 256, 0, stream>>>(Qb, Kb, Vt, gates, Og);

  dim3 g2(DIM_ / 64, (B_ * N_) / 128);   // 16 x 32 = 512 blocks
  k_gemmT<float><<<g2, 256, 0, stream>>>(Og, wot, out, B_ * N_, DIM_, DI_);
}

// Round 12
// 64.789 us; speedup vs baseline: 1.1173x; 1.1173x over previous
//
#include <hip/hip_runtime.h>

#define B_ 2
#define N_ 2048
#define DIM_ 1024
#define H_ 8
#define DH_ 64
#define DI_ 512
#define WIN_ 512
#define NCPAD 1664  // 13*128 padded proj cols: 512 q | 1024 kv | 8 g | 8 mix | 112 pad

typedef __bf16 bf16x8 __attribute__((ext_vector_type(8)));
typedef unsigned short ushortx8 __attribute__((ext_vector_type(8)));
typedef float floatx4 __attribute__((ext_vector_type(4)));

#define MFMA16(a, b, c) __builtin_amdgcn_mfma_f32_16x16x32_bf16((a), (b), (c), 0, 0, 0)

__device__ inline unsigned short f2bf(float f) {
  union { float f; unsigned u; } v; v.f = f;
  unsigned r = v.u + 0x7FFFu + ((v.u >> 16) & 1u);
  return (unsigned short)(r >> 16);
}
__device__ inline float bf2f(unsigned short u) {
  union { unsigned u; float f; } v; v.u = ((unsigned)u) << 16; return v.f;
}
__device__ inline float sigmoidf_(float x) { return 1.0f / (1.0f + __expf(-x)); }

__device__ __forceinline__ void gload_lds16(const unsigned short* g, unsigned short* l) {
  __builtin_amdgcn_global_load_lds(
      (const __attribute__((address_space(1))) void*)g,
      (__attribute__((address_space(3))) void*)l,
      16, 0, 0);
}

// ================= fused prep: trig table | tokens->bf16 | weight transposes =================
__global__ __launch_bounds__(256) void k_prep(const float* __restrict__ tokens,
                                              const float* __restrict__ Wq,
                                              const float* __restrict__ Wkv,
                                              const float* __restrict__ Wo,
                                              const float* __restrict__ Wg,
                                              const float* __restrict__ Wmix,
                                              unsigned short* __restrict__ tokb,
                                              unsigned short* __restrict__ wcat,
                                              unsigned short* __restrict__ wot,
                                              float2* __restrict__ cs) {
  __shared__ float t32[32][33];
  const int bid = blockIdx.x;
  const int tid = threadIdx.x;
  if (bid < 256) {
    int i = bid * 256 + tid;
    int n = i >> 5, t2 = i & 31;
    float inv = __expf(-(float)t2 * 0.2878231366242557f);  // ln(10000)/32
    float sv, cv;
    sincosf((float)n * inv, &sv, &cv);
    cs[i] = make_float2(cv, sv);
    return;
  }
  if (bid < 4352) {
    int i = (bid - 256) * 256 + tid;
    float4 v = reinterpret_cast<const float4*>(tokens)[i];
    ushort4 r;
    r.x = f2bf(v.x); r.y = f2bf(v.y); r.z = f2bf(v.z); r.w = f2bf(v.w);
    reinterpret_cast<ushort4*>(tokb)[i] = r;
    return;
  }
  if (bid >= 6400) {
    int idx = (bid - 6400) * 256 + tid;
    int j = idx >> 10;
    int c = idx & 1023;
    float v = (j < 8) ? Wg[c * 8 + j] : Wmix[c * 8 + (j - 8)];
    wcat[(size_t)(1536 + j) * 1024 + c] = f2bf(v);
    return;
  }
  const float* in;
  unsigned short* out;
  int Rin, Cin, c0, r0;
  if (bid < 4864) {
    int t = bid - 4352; in = Wq; out = wcat; Rin = 1024; Cin = 512;
    c0 = (t & 15) * 32; r0 = (t >> 4) * 32;
  } else if (bid < 5888) {
    int t = bid - 4864; in = Wkv; out = wcat + 512 * 1024; Rin = 1024; Cin = 1024;
    c0 = (t & 31) * 32; r0 = (t >> 5) * 32;
  } else {
    int t = bid - 5888; in = Wo; out = wot; Rin = 512; Cin = 1024;
    c0 = (t & 31) * 32; r0 = (t >> 5) * 32;
  }
  const int tx = tid & 31, ty = tid >> 5;
#pragma unroll
  for (int i = 0; i < 4; ++i)
    t32[ty + i * 8][tx] = in[(size_t)(r0 + ty + i * 8) * Cin + c0 + tx];
  __syncthreads();
#pragma unroll
  for (int i = 0; i < 4; ++i)
    out[(size_t)(c0 + ty + i * 8) * Rin + r0 + tx] = f2bf(t32[tx][ty + i * 8]);
}

// ======== GEMM1: 128x128 BK=64, dbuf, XOR-swizzled LDS, XCD-chunked, COUNTED-vmcnt loop ========
__global__ __launch_bounds__(256) void k_gemmP(const unsigned short* __restrict__ A,
                                               const unsigned short* __restrict__ Bt,
                                               unsigned short* __restrict__ C,
                                               int M, int Nc, int K) {
  __shared__ __align__(16) unsigned short As[2][128 * 64];
  __shared__ __align__(16) unsigned short Bs[2][128 * 64];
  const int tid = threadIdx.x;
  const int lane = tid & 63;
  const int wid = tid >> 6;
  const int nwgx = gridDim.x;
  const int flat = blockIdx.y * nwgx + blockIdx.x;
  const int cpx = (nwgx * gridDim.y) >> 3;
  const int swz = (flat & 7) * cpx + (flat >> 3);
  const int m0 = (swz / nwgx) * 128;
  const int n0 = (swz % nwgx) * 128;
  const int wr = (wid >> 1) * 64;
  const int wc = (wid & 1) * 64;
  const int lr = lane & 15;
  const int hi = lane >> 4;
  const int grow = tid >> 3;
  const int gchk = tid & 7;
  const int csw = gchk ^ (grow & 7);
  const unsigned short* aP = A + (size_t)(m0 + grow) * K + csw * 8;
  const unsigned short* bP = Bt + (size_t)(n0 + grow) * K + csw * 8;
  const int ldst = grow * 64 + gchk * 8;
  const int off0 = ((hi ^ (lr & 7)) << 3);
  floatx4 acc[4][4] = {};
  const int T = K >> 6;
#pragma unroll
  for (int r = 0; r < 4; ++r) {
    gload_lds16(aP + (size_t)(r * 32) * K, &As[0][ldst + r * 2048]);
    gload_lds16(bP + (size_t)(r * 32) * K, &Bs[0][ldst + r * 2048]);
  }
  for (int t = 0; t < T; ++t) {
    const int cur = t & 1;
    // barrier1: all waves' ds_reads of buf[nxt] (from iter t-1) have landed -> overwrite safe
    asm volatile("s_waitcnt lgkmcnt(0)" ::: "memory");
    __builtin_amdgcn_sched_barrier(0);
    __builtin_amdgcn_s_barrier();
    __builtin_amdgcn_sched_barrier(0);
    if (t + 1 < T) {
      const int nxt = cur ^ 1;
      const int k1 = (t + 1) << 6;
#pragma unroll
      for (int r = 0; r < 4; ++r) {
        gload_lds16(aP + k1 + (size_t)(r * 32) * K, &As[nxt][ldst + r * 2048]);
        gload_lds16(bP + k1 + (size_t)(r * 32) * K, &Bs[nxt][ldst + r * 2048]);
      }
      // wait only for stage(t)'s 8 loads (issued a full iteration ago); keep 8 new in flight
      asm volatile("s_waitcnt vmcnt(8)" ::: "memory");
    } else {
      asm volatile("s_waitcnt vmcnt(0)" ::: "memory");
    }
    __builtin_amdgcn_sched_barrier(0);
    __builtin_amdgcn_s_barrier();   // barrier2: buf[cur] fully staged by all waves
    __builtin_amdgcn_sched_barrier(0);
#pragma unroll
    for (int kk = 0; kk < 2; ++kk) {
      const int off = off0 ^ (kk << 5);
      bf16x8 af[4], bfr[4];
#pragma unroll
      for (int i = 0; i < 4; ++i)
        af[i] = *reinterpret_cast<const bf16x8*>(&As[cur][(wr + i * 16 + lr) * 64 + off]);
#pragma unroll
      for (int j = 0; j < 4; ++j)
        bfr[j] = *reinterpret_cast<const bf16x8*>(&Bs[cur][(wc + j * 16 + lr) * 64 + off]);
#pragma unroll
      for (int i = 0; i < 4; ++i)
#pragma unroll
        for (int j = 0; j < 4; ++j)
          acc[i][j] = MFMA16(af[i], bfr[j], acc[i][j]);
    }
  }
  const int r0 = hi << 2;
#pragma unroll
  for (int i = 0; i < 4; ++i)
#pragma unroll
    for (int j = 0; j < 4; ++j) {
      unsigned short* cp = C + (size_t)(m0 + wr + i * 16 + r0) * Nc + n0 + wc + j * 16 + lr;
#pragma unroll
      for (int r = 0; r < 4; ++r) cp[(size_t)r * Nc] = f2bf(acc[i][j][r]);
    }
}

// ======== GEMM2: 128x64 BK=64, dbuf, XOR-swizzled LDS, XCD-chunked, COUNTED-vmcnt loop ========
__global__ __launch_bounds__(256) void k_gemmB(const unsigned short* __restrict__ A,
                                               const unsigned short* __restrict__ Bt,
                                               float* __restrict__ C,
                                               int M, int Nc, int K) {
  __shared__ __align__(16) unsigned short As[2][128 * 64];
  __shared__ __align__(16) unsigned short Bs[2][64 * 64];
  const int tid = threadIdx.x;
  const int lane = tid & 63;
  const int wid = tid >> 6;
  const int nwgx = gridDim.x;
  const int flat = blockIdx.y * nwgx + blockIdx.x;
  const int cpx = (nwgx * gridDim.y) >> 3;
  const int swz = (flat & 7) * cpx + (flat >> 3);
  const int m0 = (swz / nwgx) * 128;
  const int n0 = (swz % nwgx) * 64;
  const int wr = (wid >> 1) * 64;
  const int wc = (wid & 1) * 32;
  const int lr = lane & 15;
  const int hi = lane >> 4;
  const int grow = tid >> 3;
  const int gchk = tid & 7;
  const int csw = gchk ^ (grow & 7);
  const unsigned short* aP = A + (size_t)(m0 + grow) * K + csw * 8;
  const unsigned short* bP = Bt + (size_t)(n0 + grow) * K + csw * 8;
  const int ldst = grow * 64 + gchk * 8;
  const int off0 = ((hi ^ (lr & 7)) << 3);
  floatx4 acc[4][2] = {};
  const int T = K >> 6;
#pragma unroll
  for (int r = 0; r < 4; ++r) gload_lds16(aP + (size_t)(r * 32) * K, &As[0][ldst + r * 2048]);
#pragma unroll
  for (int r = 0; r < 2; ++r) gload_lds16(bP + (size_t)(r * 32) * K, &Bs[0][ldst + r * 2048]);
  for (int t = 0; t < T; ++t) {
    const int cur = t & 1;
    asm volatile("s_waitcnt lgkmcnt(0)" ::: "memory");
    __builtin_amdgcn_sched_barrier(0);
    __builtin_amdgcn_s_barrier();
    __builtin_amdgcn_sched_barrier(0);
    if (t + 1 < T) {
      const int nxt = cur ^ 1;
      const int k1 = (t + 1) << 6;
#pragma unroll
      for (int r = 0; r < 4; ++r) gload_lds16(aP + k1 + (size_t)(r * 32) * K, &As[nxt][ldst + r * 2048]);
#pragma unroll
      for (int r = 0; r < 2; ++r) gload_lds16(bP + k1 + (size_t)(r * 32) * K, &Bs[nxt][ldst + r * 2048]);
      asm volatile("s_waitcnt vmcnt(6)" ::: "memory");
    } else {
      asm volatile("s_waitcnt vmcnt(0)" ::: "memory");
    }
    __builtin_amdgcn_sched_barrier(0);
    __builtin_amdgcn_s_barrier();
    __builtin_amdgcn_sched_barrier(0);
#pragma unroll
    for (int kk = 0; kk < 2; ++kk) {
      const int off = off0 ^ (kk << 5);
      bf16x8 af[4], bfr[2];
#pragma unroll
      for (int i = 0; i < 4; ++i)
        af[i] = *reinterpret_cast<const bf16x8*>(&As[cur][(wr + i * 16 + lr) * 64 + off]);
#pragma unroll
      for (int j = 0; j < 2; ++j)
        bfr[j] = *reinterpret_cast<const bf16x8*>(&Bs[cur][(wc + j * 16 + lr) * 64 + off]);
#pragma unroll
      for (int i = 0; i < 4; ++i)
#pragma unroll
        for (int j = 0; j < 2; ++j)
          acc[i][j] = MFMA16(af[i], bfr[j], acc[i][j]);
    }
  }
  const int r0 = hi << 2;
#pragma unroll
  for (int i = 0; i < 4; ++i)
#pragma unroll
    for (int j = 0; j < 2; ++j) {
      float* cp = C + (size_t)(m0 + wr + i * 16 + r0) * Nc + n0 + wc + j * 16 + lr;
#pragma unroll
      for (int r = 0; r < 4; ++r) cp[(size_t)r * Nc] = acc[i][j][r];
    }
}

// ================= fused post: RoPE Q/K + gates + V lerp/tile =================
__global__ __launch_bounds__(512) void k_postv(const unsigned short* __restrict__ proj,
                                               const float* __restrict__ vres,
                                               const float2* __restrict__ cs,
                                               unsigned short* __restrict__ Qb,
                                               unsigned short* __restrict__ Kb,
                                               unsigned short* __restrict__ Vt,
                                               float* __restrict__ gates) {
  const int w = threadIdx.x >> 6, l = threadIdx.x & 63;
  const int row = blockIdx.x * 8 + w;
  const int b = row >> 11, n = row & (N_ - 1);
  const unsigned short* pr = proj + (size_t)row * NCPAD;
  if (l < H_) gates[(size_t)(b * H_ + l) * N_ + n] = sigmoidf_(bf2f(pr[1536 + l]));
  ushortx8 qv = *reinterpret_cast<const ushortx8*>(pr + 8 * l);
  ushortx8 kv = *reinterpret_cast<const ushortx8*>(pr + 512 + 8 * l);
  const int t2b = 4 * (l & 7);
  ushortx8 qo, ko;
#pragma unroll
  for (int p = 0; p < 4; ++p) {
    float2 c2 = cs[n * 32 + t2b + p];
    float q0 = bf2f(qv[2 * p]), q1 = bf2f(qv[2 * p + 1]);
    float k0 = bf2f(kv[2 * p]), k1 = bf2f(kv[2 * p + 1]);
    qo[2 * p]     = f2bf((q0 * c2.x - q1 * c2.y) * 0.125f);
    qo[2 * p + 1] = f2bf((q1 * c2.x + q0 * c2.y) * 0.125f);
    ko[2 * p]     = f2bf(k0 * c2.x - k1 * c2.y);
    ko[2 * p + 1] = f2bf(k1 * c2.x + k0 * c2.y);
  }
  const int h = l >> 3;
  const size_t off = ((size_t)(b * H_ + h) * N_ + n) * DH_ + 8 * (l & 7);
  *reinterpret_cast<ushortx8*>(Qb + off) = qo;
  *reinterpret_cast<ushortx8*>(Kb + off) = ko;
  const int hv = w;
  const int d = l;
  const int base_row = blockIdx.x * 8;
  const int bb = base_row >> 11;
  ushortx8 acc;
#pragma unroll
  for (int r = 0; r < 8; ++r) {
    const unsigned short* pr2 = proj + (size_t)(base_row + r) * NCPAD;
    const float mix = sigmoidf_(bf2f(pr2[1544 + hv]));
    const float pv = bf2f(pr2[1024 + hv * 64 + d]);
    const float vr = vres[((size_t)(bb * H_ + hv) * N_ + ((base_row + r) & (N_ - 1))) * DH_ + d];
    acc[r] = f2bf(pv + (vr - pv) * mix);
  }
  *reinterpret_cast<ushortx8*>(Vt + (size_t)(bb * H_ + hv) * N_ * DH_ +
                               (size_t)(blockIdx.x & 255) * 512 + d * 8) = acc;
}

// ================= 4-wave LDS-staged windowed attention =================
__global__ __launch_bounds__(256) void k_attn4(const unsigned short* __restrict__ Qb,
                                               const unsigned short* __restrict__ Kb,
                                               const unsigned short* __restrict__ Vt,
                                               const float* __restrict__ gates,
                                               unsigned short* __restrict__ Og) {
  __shared__ __align__(16) unsigned short Ks[2][64 * 64];
  __shared__ __align__(16) unsigned short Vs[2][64 * 64];
  __shared__ __align__(16) unsigned short Ps[4][16 * 72];
  const int bid = (int)blockIdx.x;
  const int xcd = bid & 7;
  const int seq = bid >> 3;
  const int bh = xcd * 2 + (seq >> 5);
  const int s = seq & 31;
  const int qt = (s & 1) ? (s >> 1) : (31 - (s >> 1));
  const int b = bh >> 3, h = bh & 7;
  const int qi0 = qt * 64;
  const int tid = threadIdx.x;
  const int w = tid >> 6;
  const int lane = tid & 63;
  const int lr = lane & 15;
  const int hi = lane >> 4;
  const int lk = hi << 3;
  const int qw0 = qi0 + w * 16;
  const unsigned short* Qh = Qb + (size_t)bh * N_ * DH_;
  const unsigned short* Kh = Kb + (size_t)bh * N_ * DH_;
  const unsigned short* Vh = Vt + (size_t)bh * N_ * DH_;
  bf16x8 aq0 = *reinterpret_cast<const bf16x8*>(Qh + (qw0 + lr) * DH_ + lk);
  bf16x8 aq1 = *reinterpret_cast<const bf16x8*>(Qh + (qw0 + lr) * DH_ + 32 + lk);
  floatx4 o[4] = {};
  float lsum[4] = {0.f, 0.f, 0.f, 0.f};

  const int s_row = tid >> 3;
  const int s_chk = tid & 7;

  auto stage = [&](int bufi, int j0) {
#pragma unroll
    for (int p = 0; p < 2; ++p) {
      const int row = s_row + p * 32;
      const int csw = s_chk ^ (row & 7);
      gload_lds16(Kh + (size_t)(j0 + row) * DH_ + csw * 8, &Ks[bufi][(row * 8 + s_chk) * 8]);
    }
#pragma unroll
    for (int p = 0; p < 2; ++p) {
      const int flat = p * 256 + tid;
      gload_lds16(Vh + (size_t)j0 * DH_ + flat * 8, &Vs[bufi][flat * 8]);
    }
  };

  auto compute = [&](int bufi, int j0, bool maskLo, bool maskHi) {
    floatx4 c[4];
    __builtin_amdgcn_s_setprio(1);
#pragma unroll
    for (int cc = 0; cc < 4; ++cc) {
      const int row = 16 * cc + lr;
      const int sw = row & 7;
      bf16x8 kf0 = *reinterpret_cast<const bf16x8*>(&Ks[bufi][row * 64 + ((hi ^ sw) << 3)]);
      bf16x8 kf1 = *reinterpret_cast<const bf16x8*>(&Ks[bufi][row * 64 + (((hi + 4) ^ sw) << 3)]);
      floatx4 a = {};
      a = MFMA16(aq0, kf0, a);
      a = MFMA16(aq1, kf1, a);
      c[cc] = a;
    }
    __builtin_amdgcn_s_setprio(0);
#pragma unroll
    for (int cc = 0; cc < 4; ++cc)
#pragma unroll
      for (int r = 0; r < 4; ++r) {
        const int i = qw0 + hi * 4 + r;
        const int j = j0 + 16 * cc + lr;
        float sc = c[cc][r];
        if (maskHi && j > i) sc = -1e30f;
        if (maskLo && (i - j) > WIN_) sc = -1e30f;
        const float p = __expf(sc);
        lsum[r] += p;
        Ps[w][(hi * 4 + r) * 72 + 16 * cc + lr] = f2bf(p);
      }
    bf16x8 pa0 = *reinterpret_cast<const bf16x8*>(&Ps[w][lr * 72 + lk]);
    bf16x8 pa1 = *reinterpret_cast<const bf16x8*>(&Ps[w][lr * 72 + 32 + lk]);
    __builtin_amdgcn_s_setprio(1);
#pragma unroll
    for (int nb = 0; nb < 4; ++nb) {
      bf16x8 v0 = *reinterpret_cast<const bf16x8*>(&Vs[bufi][lk * 64 + nb * 128 + lr * 8]);
      bf16x8 v1 = *reinterpret_cast<const bf16x8*>(&Vs[bufi][(32 + lk) * 64 + nb * 128 + lr * 8]);
      o[nb] = MFMA16(pa0, v0, o[nb]);
      o[nb] = MFMA16(pa1, v1, o[nb]);
    }
    __builtin_amdgcn_s_setprio(0);
  };

  const int jlo = (qi0 >= WIN_) ? (qi0 - WIN_) : 0;
  const int niter = (qi0 + 64 - jlo) >> 6;
  const bool needLo = (qi0 >= WIN_);

  stage(0, jlo);
  __syncthreads();
  int bufi = 0;
  for (int t = 0; t < niter; ++t) {
    const int j0 = jlo + t * 64;
    if (t + 1 < niter) stage(bufi ^ 1, j0 + 64);
    compute(bufi, j0, needLo && t == 0, t == niter - 1);
    __syncthreads();
    bufi ^= 1;
  }

#pragma unroll
  for (int r = 0; r < 4; ++r) {
    float ls = lsum[r];
#pragma unroll
    for (int off = 1; off < 16; off <<= 1) ls += __shfl_xor(ls, off, 16);
    const int i = qw0 + hi * 4 + r;
    const float g = gates[(size_t)bh * N_ + i] * __builtin_amdgcn_rcpf(ls);
#pragma unroll
    for (int nb = 0; nb < 4; ++nb)
      Og[((size_t)(b * N_ + i)) * DI_ + h * DH_ + nb * 16 + lr] = f2bf(o[nb][r] * g);
  }
}

extern "C" void kernel_launch(void* const* d_in, const int* in_sizes, int n_in,
                              void* d_out, int out_size, void* d_ws, size_t ws_size,
                              hipStream_t stream) {
  const float* tokens = (const float*)d_in[0];
  const float* vres   = (const float*)d_in[1];
  const float* Wq     = (const float*)d_in[2];
  const float* Wkv    = (const float*)d_in[3];
  const float* Wo     = (const float*)d_in[4];
  const float* Wg     = (const float*)d_in[5];
  const float* Wmix   = (const float*)d_in[6];
  float* out = (float*)d_out;
  char* ws = (char*)d_ws;
  unsigned short* tokb = (unsigned short*)(ws);              // 8,388,608
  unsigned short* wcat = (unsigned short*)(ws + 8388608);    // 3,407,872
  unsigned short* wot  = (unsigned short*)(ws + 11796480);   // 1,048,576
  unsigned short* proj = (unsigned short*)(ws + 12845056);   // 13,631,488
  unsigned short* Qb   = (unsigned short*)(ws + 26476544);   // 4,194,304
  unsigned short* Kb   = (unsigned short*)(ws + 30670848);   // 4,194,304
  unsigned short* Vt   = (unsigned short*)(ws + 34865152);   // 4,194,304
  float*          gates= (float*)(ws + 39059456);            // 131,072
  unsigned short* Og   = (unsigned short*)(ws + 39190528);   // 4,194,304
  float2*         cs   = (float2*)(ws + 43384832);           // 524,288
  (void)in_sizes; (void)n_in; (void)out_size; (void)ws_size;

  k_prep<<<6464, 256, 0, stream>>>(tokens, Wq, Wkv, Wo, Wg, Wmix, tokb, wcat, wot, cs);

  dim3 g1(NCPAD / 128, (B_ * N_) / 128);  // 13 x 32 = 416 blocks
  k_gemmP<<<g1, 256, 0, stream>>>(tokb, wcat, proj, B_ * N_, NCPAD, DIM_);

  k_postv<<<(B_ * N_) / 8, 512, 0, stream>>>(proj, vres, cs, Qb, Kb, Vt, gates);

  k_attn4<<<512, 256, 0, stream>>>(Qb, Kb, Vt, gates, Og);

  dim3 g2(DIM_ / 64, (B_ * N_) / 128);    // 16 x 32 = 512 blocks
  k_gemmB<<<g2, 256, 0, stream>>>(Og, wot, out, B_ * N_, DIM_, DI_);
}